// Round 3
// baseline (1954.941 us; speedup 1.0000x reference)
//
#include <hip/hip_runtime.h>

typedef __attribute__((ext_vector_type(8))) short short8;
typedef __attribute__((ext_vector_type(4))) float f32x4;

#define DEV static __device__ __forceinline__

DEV unsigned short f2bf(float x) {
  union { float f; unsigned int u; } c; c.f = x;
  unsigned int r = c.u + 0x7fffu + ((c.u >> 16) & 1u);
  return (unsigned short)(r >> 16);
}
DEV float bf2f(unsigned short s) {
  union { unsigned int u; float f; } c; c.u = ((unsigned int)s) << 16;
  return c.f;
}
DEV float elu1(float x) { return x > 0.f ? x + 1.f : __expf(x); }

DEV void gload_lds16(const void* g, void* l) {
  __builtin_amdgcn_global_load_lds(
      (const __attribute__((address_space(1))) unsigned int*)g,
      (__attribute__((address_space(3))) unsigned int*)l, 16, 0, 0);
}

// ---------------- weight transpose + bf16 convert: dst[layer][N][K] = src[layer][K][N]
__global__ __launch_bounds__(256)
void wprep(const float* __restrict__ src, unsigned short* __restrict__ dst,
           int K, int N, int dls) {
  const int layer = blockIdx.z;
  src += (size_t)layer * K * N;
  dst += (size_t)layer * dls;
  __shared__ float tile[64][65];
  const int n0 = blockIdx.x * 64, k0 = blockIdx.y * 64;
  const int c = threadIdx.x & 63, r4 = threadIdx.x >> 6;
#pragma unroll
  for (int i = 0; i < 16; ++i) {
    int r = (i << 2) + r4;
    tile[r][c] = src[(size_t)(k0 + r) * N + n0 + c];
  }
  __syncthreads();
#pragma unroll
  for (int i = 0; i < 16; ++i) {
    int r = (i << 2) + r4;
    dst[(size_t)(n0 + r) * K + k0 + c] = f2bf(tile[c][r]);
  }
}

// ---------------- init: f32 copy + bf16 mirror
__global__ __launch_bounds__(256)
void init_feat(const float* __restrict__ src, float* __restrict__ dstf,
               unsigned short* __restrict__ dstb, int n4) {
  int i = blockIdx.x * 256 + threadIdx.x;
  if (i >= n4) return;
  float4 v = ((const float4*)src)[i];
  ((float4*)dstf)[i] = v;
  ushort4 o;
  o.x = f2bf(v.x); o.y = f2bf(v.y); o.z = f2bf(v.z); o.w = f2bf(v.w);
  ((ushort4*)dstb)[i] = o;
}

// ---------------- zero helper
__global__ __launch_bounds__(256)
void zero_f4(float* __restrict__ p, int n4) {
  int i = blockIdx.x * 256 + threadIdx.x;
  if (i < n4) ((float4*)p)[i] = make_float4(0.f, 0.f, 0.f, 0.f);
}

// ---------------- bf16 MFMA GEMM, BT input (B stored N x K), 128x128 tile, BK=64
// EPI: 1 = relu->bf16 (stride N); 3 = elu->bf16 (stride 256)
template<int EPI>
__global__ __launch_bounds__(256)
void gemm_bt(const unsigned short* __restrict__ A0,
             const unsigned short* __restrict__ A1,   // concat half (k>=256), stride 256; or null
             const unsigned short* __restrict__ BT,
             unsigned short* __restrict__ Cb,
             int M, int N, int K, int lda) {
  __shared__ __align__(16) unsigned short As[128 * 64];
  __shared__ __align__(16) unsigned short Bs[128 * 64];
  const int tid = threadIdx.x;
  const int lane = tid & 63, wave = tid >> 6;
  const int tn = N >> 7;
  const int bm = (int)blockIdx.x / tn, bn = (int)blockIdx.x % tn;
  const int wm = (wave >> 1) << 6, wn = (wave & 1) << 6;
  const int lr = lane & 15, lk = lane >> 4;

  f32x4 acc[4][4];
#pragma unroll
  for (int i = 0; i < 4; ++i)
#pragma unroll
    for (int j = 0; j < 4; ++j) acc[i][j] = (f32x4){0.f, 0.f, 0.f, 0.f};

  for (int k0 = 0; k0 < K; k0 += 64) {
#pragma unroll
    for (int i = 0; i < 4; ++i) {
      const int cb = (i << 2) + wave;
      const int id = (cb << 6) + lane;
      const int row = id >> 3, ck = id & 7;
      const int gk = k0 + ((ck ^ (row & 7)) << 3);
      const unsigned short* srcA;
      if (A1) {
        srcA = (gk < 256) ? (A0 + (size_t)(bm * 128 + row) * 256 + gk)
                          : (A1 + (size_t)(bm * 128 + row) * 256 + (gk - 256));
      } else {
        srcA = A0 + (size_t)(bm * 128 + row) * lda + gk;
      }
      gload_lds16(srcA, As + (size_t)cb * 512);
      const unsigned short* srcB = BT + (size_t)(bn * 128 + row) * K + gk;
      gload_lds16(srcB, Bs + (size_t)cb * 512);
    }
    __syncthreads();
#pragma unroll
    for (int kk = 0; kk < 2; ++kk) {
      short8 af[4], bfr[4];
#pragma unroll
      for (int mi = 0; mi < 4; ++mi) {
        const int row = wm + mi * 16 + lr;
        const int ck = ((kk << 2) + lk) ^ (row & 7);
        af[mi] = *(const short8*)(As + row * 64 + ck * 8);
      }
#pragma unroll
      for (int ni = 0; ni < 4; ++ni) {
        const int row = wn + ni * 16 + lr;
        const int ck = ((kk << 2) + lk) ^ (row & 7);
        bfr[ni] = *(const short8*)(Bs + row * 64 + ck * 8);
      }
#pragma unroll
      for (int mi = 0; mi < 4; ++mi)
#pragma unroll
        for (int ni = 0; ni < 4; ++ni)
          acc[mi][ni] = __builtin_amdgcn_mfma_f32_16x16x32_bf16(af[mi], bfr[ni], acc[mi][ni], 0, 0, 0);
    }
    __syncthreads();
  }

  const int cr = lk << 2;
#pragma unroll
  for (int mi = 0; mi < 4; ++mi) {
#pragma unroll
    for (int ni = 0; ni < 4; ++ni) {
      const int colbase = bn * 128 + wn + ni * 16;
#pragma unroll
      for (int j = 0; j < 4; ++j) {
        const int row = bm * 128 + wm + mi * 16 + cr + j;
        const int col = colbase + lr;
        float v = acc[mi][ni][j];
        if (EPI == 1) {
          Cb[(size_t)row * N + col] = f2bf(fmaxf(v, 0.f));
        } else {
          Cb[(size_t)row * 256 + col] = f2bf(elu1(v));
        }
      }
    }
  }
}

// ---------------- K/V projection GEMM with fused KV/Ksum reduction (no C write).
// BM=128 (s rows), BN=512 (= all K|V cols), 8 waves. Per batch n (grid.y),
// grid.x = 38 blocks of 128 rows (last block: 64 valid). Epilogue: stage tile
// to LDS as bf16 (elu on K cols), per-wave head outer-product, atomicAdd f32.
__global__ __launch_bounds__(512)
void gemm_kv(const unsigned short* __restrict__ A, const unsigned short* __restrict__ BT,
             float* __restrict__ KVf, float* __restrict__ Ksumf) {
  __shared__ __align__(16) unsigned short sh[40960];  // 80 KiB
  unsigned short* As = sh;             // [128][64]
  unsigned short* Bs = sh + 128 * 64;  // [512][64]
  const int tid = threadIdx.x, lane = tid & 63, wid = tid >> 6;
  const int n = blockIdx.y, bm = blockIdx.x;
  const int wm = (wid >> 2) << 6, wn = (wid & 3) << 7;
  const int lr = lane & 15, lk = lane >> 4;
  const int row0 = bm * 128;
  const int valid = min(128, 4800 - row0);
  const unsigned short* Ab = A + ((size_t)n * 4800 + row0) * 256;

  f32x4 acc[4][8];
#pragma unroll
  for (int i = 0; i < 4; ++i)
#pragma unroll
    for (int j = 0; j < 8; ++j) acc[i][j] = (f32x4){0.f, 0.f, 0.f, 0.f};

  for (int k0 = 0; k0 < 256; k0 += 64) {
#pragma unroll
    for (int j = 0; j < 2; ++j) {
      int c = j * 512 + tid;
      int row = c >> 3, ck = c & 7;
      int gk = k0 + ((ck ^ (row & 7)) << 3);
      gload_lds16(Ab + (size_t)row * 256 + gk, As + (size_t)c * 8);
    }
#pragma unroll
    for (int j = 0; j < 8; ++j) {
      int c = j * 512 + tid;
      int row = c >> 3, ck = c & 7;
      int gk = k0 + ((ck ^ (row & 7)) << 3);
      gload_lds16(BT + (size_t)row * 256 + gk, Bs + (size_t)c * 8);
    }
    __syncthreads();
#pragma unroll
    for (int kk = 0; kk < 2; ++kk) {
      short8 af[4], bfr[8];
#pragma unroll
      for (int mi = 0; mi < 4; ++mi) {
        int row = wm + mi * 16 + lr;
        int ck = ((kk << 2) + lk) ^ (row & 7);
        af[mi] = *(const short8*)(As + row * 64 + ck * 8);
      }
#pragma unroll
      for (int ni = 0; ni < 8; ++ni) {
        int row = wn + ni * 16 + lr;
        int ck = ((kk << 2) + lk) ^ (row & 7);
        bfr[ni] = *(const short8*)(Bs + row * 64 + ck * 8);
      }
#pragma unroll
      for (int mi = 0; mi < 4; ++mi)
#pragma unroll
        for (int ni = 0; ni < 8; ++ni)
          acc[mi][ni] = __builtin_amdgcn_mfma_f32_16x16x32_bf16(af[mi], bfr[ni], acc[mi][ni], 0, 0, 0);
    }
    __syncthreads();
  }

  const int cr = lk << 2;
  const int dq = lane >> 3, vq = lane & 7;
  float a[4][4], ks[4] = {0.f, 0.f, 0.f, 0.f};
#pragma unroll
  for (int i = 0; i < 4; ++i)
#pragma unroll
    for (int j = 0; j < 4; ++j) a[i][j] = 0.f;

#pragma unroll
  for (int th = 0; th < 2; ++th) {
    if ((wm >> 6) == th) {
#pragma unroll
      for (int mi = 0; mi < 4; ++mi)
#pragma unroll
        for (int j = 0; j < 4; ++j) {
          int r = mi * 16 + cr + j;
          bool dead = (th * 64 + r) >= valid;
#pragma unroll
          for (int ni = 0; ni < 8; ++ni) {
            int col = wn + ni * 16 + lr;
            float v = acc[mi][ni][j];
            sh[r * 512 + col] = dead ? (unsigned short)0
                                     : f2bf(col < 256 ? elu1(v) : v);
          }
        }
    }
    __syncthreads();
    const unsigned short* kbase = sh + wid * 32 + dq * 4;
    const unsigned short* vbase = sh + 256 + wid * 32 + vq * 4;
    for (int s = 0; s < 64; ++s) {
      float kr[4], vr[4];
#pragma unroll
      for (int e = 0; e < 4; ++e) kr[e] = bf2f(kbase[s * 512 + e]);
#pragma unroll
      for (int e = 0; e < 4; ++e) vr[e] = bf2f(vbase[s * 512 + e]);
      ks[0] += kr[0]; ks[1] += kr[1]; ks[2] += kr[2]; ks[3] += kr[3];
#pragma unroll
      for (int i = 0; i < 4; ++i)
#pragma unroll
        for (int j = 0; j < 4; ++j) a[i][j] += kr[i] * vr[j];
    }
    __syncthreads();
  }

  float* kvd = KVf + (size_t)(n * 8 + wid) * 1024;
  float* ksd = Ksumf + (size_t)(n * 8 + wid) * 32;
#pragma unroll
  for (int i = 0; i < 4; ++i) {
#pragma unroll
    for (int j = 0; j < 4; ++j)
      atomicAdd(&kvd[(dq * 4 + i) * 32 + vq * 4 + j], a[i][j]);
    if (vq == 0) atomicAdd(&ksd[dq * 4 + i], ks[i]);
  }
}

// ---------------- KV f32 -> bf16 in MFMA B-fragment order
__global__ __launch_bounds__(256)
void kv_cvt(const float* __restrict__ KVf, unsigned short* __restrict__ KVb) {
  const int nh = blockIdx.x, t = threadIdx.x;
  const float* src = KVf + (size_t)nh * 1024;
#pragma unroll
  for (int j = 0; j < 4; ++j) {
    int e = t * 4 + j;
    float s = src[e];
    int dd = e >> 5, vv = e & 31;
    size_t addr = ((size_t)(nh * 2 + (vv >> 4)) * 64 + ((dd >> 3) * 16 + (vv & 15))) * 8 + (dd & 7);
    KVb[addr] = f2bf(s);
  }
}

// ---------------- fused GEMM (N=256 exactly) + LayerNorm epilogue.
// BM=128, BN=256, 8 waves (512 thr). EPI 0: LN -> bf16; EPI 1: residual + LN -> f32 + bf16
template<int EPI>
__global__ __launch_bounds__(512)
void gemm_ln(const unsigned short* __restrict__ A, const unsigned short* __restrict__ BT,
             const float* __restrict__ lnw, const float* __restrict__ lnb,
             const float* __restrict__ xres, float* __restrict__ outf,
             unsigned short* __restrict__ outb, int K) {
  __shared__ __align__(16) unsigned short As[128 * 64];
  __shared__ __align__(16) unsigned short Bs[256 * 64];
  const int tid = threadIdx.x;
  const int lane = tid & 63, wid = tid >> 6;
  const int bm = blockIdx.x;
  const int wm = (wid >> 2) << 6, wn = (wid & 3) << 6;
  const int lr = lane & 15, lk = lane >> 4;

  f32x4 acc[4][4];
#pragma unroll
  for (int i = 0; i < 4; ++i)
#pragma unroll
    for (int j = 0; j < 4; ++j) acc[i][j] = (f32x4){0.f, 0.f, 0.f, 0.f};

  for (int k0 = 0; k0 < K; k0 += 64) {
#pragma unroll
    for (int i = 0; i < 2; ++i) {
      const int cb = i * 8 + wid;
      const int id = (cb << 6) + lane;
      const int row = id >> 3, ck = id & 7;
      const int gk = k0 + ((ck ^ (row & 7)) << 3);
      gload_lds16(A + (size_t)(bm * 128 + row) * K + gk, As + (size_t)cb * 512);
    }
#pragma unroll
    for (int i = 0; i < 4; ++i) {
      const int cb = i * 8 + wid;
      const int id = (cb << 6) + lane;
      const int row = id >> 3, ck = id & 7;
      const int gk = k0 + ((ck ^ (row & 7)) << 3);
      gload_lds16(BT + (size_t)row * K + gk, Bs + (size_t)cb * 512);
    }
    __syncthreads();
#pragma unroll
    for (int kk = 0; kk < 2; ++kk) {
      short8 af[4], bfr[4];
#pragma unroll
      for (int mi = 0; mi < 4; ++mi) {
        const int row = wm + mi * 16 + lr;
        const int ck = ((kk << 2) + lk) ^ (row & 7);
        af[mi] = *(const short8*)(As + row * 64 + ck * 8);
      }
#pragma unroll
      for (int ni = 0; ni < 4; ++ni) {
        const int row = wn + ni * 16 + lr;
        const int ck = ((kk << 2) + lk) ^ (row & 7);
        bfr[ni] = *(const short8*)(Bs + row * 64 + ck * 8);
      }
#pragma unroll
      for (int mi = 0; mi < 4; ++mi)
#pragma unroll
        for (int ni = 0; ni < 4; ++ni)
          acc[mi][ni] = __builtin_amdgcn_mfma_f32_16x16x32_bf16(af[mi], bfr[ni], acc[mi][ni], 0, 0, 0);
    }
    __syncthreads();
  }

  // ---- cross-wave LN reduce (rows complete within block; 4 wn-groups per row)
  float* red = (float*)As;  // [128][8]: per row, 4 x (sum, sumsq)
  float wv[4], bv[4];
#pragma unroll
  for (int ni = 0; ni < 4; ++ni) {
    wv[ni] = lnw[wn + ni * 16 + lr];
    bv[ni] = lnb[wn + ni * 16 + lr];
  }
#pragma unroll
  for (int mi = 0; mi < 4; ++mi) {
#pragma unroll
    for (int j = 0; j < 4; ++j) {
      float s = 0.f, q = 0.f;
#pragma unroll
      for (int ni = 0; ni < 4; ++ni) {
        float v = acc[mi][ni][j];
        s += v; q += v * v;
      }
#pragma unroll
      for (int o = 1; o < 16; o <<= 1) {
        s += __shfl_xor(s, o);
        q += __shfl_xor(q, o);
      }
      if (lr == 0) {
        int row = wm + mi * 16 + (lk << 2) + j;
        red[row * 8 + (wid & 3) * 2] = s;
        red[row * 8 + (wid & 3) * 2 + 1] = q;
      }
    }
  }
  __syncthreads();
#pragma unroll
  for (int mi = 0; mi < 4; ++mi) {
#pragma unroll
    for (int j = 0; j < 4; ++j) {
      const int row = wm + mi * 16 + (lk << 2) + j;
      const size_t grow = (size_t)bm * 128 + row;
      float s = red[row * 8] + red[row * 8 + 2] + red[row * 8 + 4] + red[row * 8 + 6];
      float q = red[row * 8 + 1] + red[row * 8 + 3] + red[row * 8 + 5] + red[row * 8 + 7];
      float mu = s * (1.f / 256.f);
      float var = q * (1.f / 256.f) - mu * mu;
      float rstd = rsqrtf(var + 1e-5f);
#pragma unroll
      for (int ni = 0; ni < 4; ++ni) {
        int col = wn + ni * 16 + lr;
        float y = (acc[mi][ni][j] - mu) * rstd * wv[ni] + bv[ni];
        if (EPI == 0) {
          outb[grow * 256 + col] = f2bf(y);
        } else {
          float o = xres[grow * 256 + col] + y;
          outf[grow * 256 + col] = o;
          outb[grow * 256 + col] = f2bf(o);
        }
      }
    }
  }
}

// ---------------- msg = (Q @ KV) * z, z = 1/(Q.Ksum + 1e-6); Q already elu'd, bf16
__global__ __launch_bounds__(256)
void msg_kernel(const unsigned short* __restrict__ qb, const unsigned short* __restrict__ KVb,
                const float* __restrict__ Ksum, unsigned short* __restrict__ msg, int qoff) {
  const int n = blockIdx.y;
  const int wave = threadIdx.x >> 6, lane = threadIdx.x & 63;
  const int lr = lane & 15, lk = lane >> 4;
  const int lrow = blockIdx.x * 64 + wave * 16 + lr;
  const unsigned short* qrow = qb + ((size_t)qoff + (size_t)n * 4800 + lrow) * 256;
  const short8* kvv = (const short8*)KVb;
  for (int h = 0; h < 8; ++h) {
    short8 af = *(const short8*)(qrow + h * 32 + lk * 8);
    const float* ksp = Ksum + (n * 8 + h) * 32 + lk * 8;
    float zp = 0.f;
#pragma unroll
    for (int j = 0; j < 8; ++j) zp += bf2f((unsigned short)af[j]) * ksp[j];
    zp += __shfl_xor(zp, 16);
    zp += __shfl_xor(zp, 32);
    float z = 1.f / (zp + 1e-6f);
    short8 b0 = kvv[((size_t)(n * 8 + h) * 2 + 0) * 64 + lane];
    short8 b1 = kvv[((size_t)(n * 8 + h) * 2 + 1) * 64 + lane];
    f32x4 acc0 = (f32x4){0.f, 0.f, 0.f, 0.f}, acc1 = (f32x4){0.f, 0.f, 0.f, 0.f};
    acc0 = __builtin_amdgcn_mfma_f32_16x16x32_bf16(af, b0, acc0, 0, 0, 0);
    acc1 = __builtin_amdgcn_mfma_f32_16x16x32_bf16(af, b1, acc1, 0, 0, 0);
#pragma unroll
    for (int j = 0; j < 4; ++j) {
      int rr = lk * 4 + j;
      float zj = __shfl(z, rr);
      int row = blockIdx.x * 64 + wave * 16 + rr;
      size_t base = ((size_t)n * 4800 + row) * 256 + h * 32;
      msg[base + lr] = f2bf(acc0[j] * zj);
      msg[base + 16 + lr] = f2bf(acc1[j] * zj);
    }
  }
}

extern "C" void kernel_launch(void* const* d_in, const int* in_sizes, int n_in,
                              void* d_out, int out_size, void* d_ws, size_t ws_size,
                              hipStream_t stream) {
  (void)in_sizes; (void)n_in; (void)out_size; (void)ws_size;
  const float* feat0 = (const float*)d_in[0];
  const float* feat1 = (const float*)d_in[1];
  const float* Wq = (const float*)d_in[2];
  const float* Wk = (const float*)d_in[3];
  const float* Wv = (const float*)d_in[4];
  const float* Wm = (const float*)d_in[5];
  const float* W1 = (const float*)d_in[6];
  const float* W2 = (const float*)d_in[7];
  const float* ln1w = (const float*)d_in[8];
  const float* ln1b = (const float*)d_in[9];
  const float* ln2w = (const float*)d_in[10];
  const float* ln2b = (const float*)d_in[11];

  float* F0 = (float*)d_out;
  float* F1 = F0 + (size_t)4915200;

  size_t off = 0;
  auto alloc = [&](size_t bytes) -> void* {
    void* p = (char*)d_ws + off;
    off += (bytes + 255) & ~(size_t)255;
    return p;
  };
  unsigned short* Fb     = (unsigned short*)alloc((size_t)38400 * 256 * 2);
  unsigned short* qb     = (unsigned short*)alloc((size_t)38400 * 256 * 2);
  unsigned short* h1b    = (unsigned short*)alloc((size_t)38400 * 512 * 2);
  unsigned short* msgb   = (unsigned short*)alloc((size_t)38400 * 256 * 2);
  unsigned short* msglnb = (unsigned short*)alloc((size_t)38400 * 256 * 2);
  float*          attn   = (float*)alloc((size_t)67584 * 4);   // KVf[64][1024] + Ksumf[64][32]
  unsigned short* KVb    = (unsigned short*)alloc((size_t)65536 * 2);
  unsigned short* WqkvT  = (unsigned short*)alloc((size_t)8 * 196608 * 2);
  unsigned short* WmT    = (unsigned short*)alloc((size_t)8 * 65536 * 2);
  unsigned short* W1T    = (unsigned short*)alloc((size_t)8 * 262144 * 2);
  unsigned short* W2T    = (unsigned short*)alloc((size_t)8 * 131072 * 2);
  float* Ksumf = attn + 65536;
  unsigned short* F0b = Fb;
  unsigned short* F1b = Fb + (size_t)19200 * 256;

  init_feat<<<4800, 256, 0, stream>>>(feat0, F0, F0b, 1228800);
  init_feat<<<4800, 256, 0, stream>>>(feat1, F1, F1b, 1228800);

  wprep<<<dim3(4, 4, 8), 256, 0, stream>>>(Wq, WqkvT, 256, 256, 196608);
  wprep<<<dim3(4, 4, 8), 256, 0, stream>>>(Wk, WqkvT + 65536, 256, 256, 196608);
  wprep<<<dim3(4, 4, 8), 256, 0, stream>>>(Wv, WqkvT + 131072, 256, 256, 196608);
  wprep<<<dim3(4, 4, 8), 256, 0, stream>>>(Wm, WmT, 256, 256, 65536);
  wprep<<<dim3(8, 8, 8), 256, 0, stream>>>(W1, W1T, 512, 512, 262144);
  wprep<<<dim3(4, 8, 8), 256, 0, stream>>>(W2, W2T, 512, 256, 131072);

  // attention block: KV/Ksum accumulation + msg; src = source-feature bf16 base,
  // nb batches, qoff = row offset into qb for the Q side
  auto attn_block = [&](const unsigned short* src, int nb, int qoff, int i) {
    zero_f4<<<66, 256, 0, stream>>>(attn, 16896);
    gemm_kv<<<dim3(38, nb), 512, 0, stream>>>(src, WqkvT + (size_t)i * 196608 + 65536,
                                              attn, Ksumf);
    kv_cvt<<<nb * 8, 256, 0, stream>>>(attn, KVb);
    msg_kernel<<<dim3(75, nb), 256, 0, stream>>>(qb, KVb, Ksumf, msgb, qoff);
  };

  // FFN tail: msg -> Wm+LN1 -> W1(relu) -> W2+LN2(+residual). M rows, Xb feature bf16.
  auto ffn = [&](unsigned short* Xb, float* X, int M, int i) {
    const int g = M >> 7;
    gemm_ln<0><<<g, 512, 0, stream>>>(msgb, WmT + (size_t)i * 65536,
                                      ln1w + i * 256, ln1b + i * 256,
                                      nullptr, nullptr, msglnb, 256);
    gemm_bt<1><<<g * 4, 256, 0, stream>>>(Xb, msglnb, W1T + (size_t)i * 262144,
                                          h1b, M, 512, 512, 256);
    gemm_ln<1><<<g, 512, 0, stream>>>(h1b, W2T + (size_t)i * 131072,
                                      ln2w + i * 256, ln2b + i * 256,
                                      X, X, Xb, 512);
  };

  for (int i = 0; i < 8; ++i) {
    // batched Q for both features (uses pre-update features in both self & cross)
    gemm_bt<3><<<600, 256, 0, stream>>>(Fb, nullptr, WqkvT + (size_t)i * 196608,
                                        qb, 38400, 256, 256, 256);
    if ((i & 1) == 0) {
      attn_block(Fb, 8, 0, i);
      ffn(Fb, F0, 38400, i);
    } else {
      attn_block(F1b, 4, 0, i);       // F0 attends to F1 (old)
      ffn(F0b, F0, 19200, i);
      attn_block(F0b, 4, 19200, i);   // F1 attends to F0 (new)
      ffn(F1b, F1, 19200, i);
    }
  }
}

// Round 4
// 1789.165 us; speedup vs baseline: 1.0927x; 1.0927x over previous
//
#include <hip/hip_runtime.h>

typedef __attribute__((ext_vector_type(8))) short short8;
typedef __attribute__((ext_vector_type(4))) float f32x4;

#define DEV static __device__ __forceinline__

DEV unsigned short f2bf(float x) {
  union { float f; unsigned int u; } c; c.f = x;
  unsigned int r = c.u + 0x7fffu + ((c.u >> 16) & 1u);
  return (unsigned short)(r >> 16);
}
DEV float bf2f(unsigned short s) {
  union { unsigned int u; float f; } c; c.u = ((unsigned int)s) << 16;
  return c.f;
}
DEV float elu1(float x) { return x > 0.f ? x + 1.f : __expf(x); }

DEV void gload_lds16(const void* g, void* l) {
  __builtin_amdgcn_global_load_lds(
      (const __attribute__((address_space(1))) unsigned int*)g,
      (__attribute__((address_space(3))) unsigned int*)l, 16, 0, 0);
}

// ---------------- weight transpose + bf16 convert: dst[layer][N][K] = src[layer][K][N]
__global__ __launch_bounds__(256)
void wprep(const float* __restrict__ src, unsigned short* __restrict__ dst,
           int K, int N, int dls) {
  const int layer = blockIdx.z;
  src += (size_t)layer * K * N;
  dst += (size_t)layer * dls;
  __shared__ float tile[64][65];
  const int n0 = blockIdx.x * 64, k0 = blockIdx.y * 64;
  const int c = threadIdx.x & 63, r4 = threadIdx.x >> 6;
#pragma unroll
  for (int i = 0; i < 16; ++i) {
    int r = (i << 2) + r4;
    tile[r][c] = src[(size_t)(k0 + r) * N + n0 + c];
  }
  __syncthreads();
#pragma unroll
  for (int i = 0; i < 16; ++i) {
    int r = (i << 2) + r4;
    dst[(size_t)(n0 + r) * K + k0 + c] = f2bf(tile[c][r]);
  }
}

// ---------------- init: f32 copy + bf16 mirror
__global__ __launch_bounds__(256)
void init_feat(const float* __restrict__ src, float* __restrict__ dstf,
               unsigned short* __restrict__ dstb, int n4) {
  int i = blockIdx.x * 256 + threadIdx.x;
  if (i >= n4) return;
  float4 v = ((const float4*)src)[i];
  ((float4*)dstf)[i] = v;
  ushort4 o;
  o.x = f2bf(v.x); o.y = f2bf(v.y); o.z = f2bf(v.z); o.w = f2bf(v.w);
  ((ushort4*)dstb)[i] = o;
}

// ---------------- bf16 MFMA GEMM, BT input (B stored N x K), 128x128 tile, BK=64,
// double-buffered prefetch (stage t+1 before computing t).
// EPI: 1 = relu->bf16 (stride N); 2 = elu on col<256 ->bf16 (stride N);
//      3 = elu->bf16 (stride 256); 4 = merged qkv: q->Cb (stride 256, elu),
//          k/v->Cb2 (stride 512, elu on col<512)
template<int EPI>
__global__ __launch_bounds__(256)
void gemm_bt(const unsigned short* __restrict__ A0,
             const unsigned short* __restrict__ A1,   // concat half (k>=256), stride 256; or null
             const unsigned short* __restrict__ BT,
             unsigned short* __restrict__ Cb, unsigned short* __restrict__ Cb2,
             int M, int N, int K, int lda) {
  __shared__ __align__(16) unsigned short As[2 * 128 * 64];
  __shared__ __align__(16) unsigned short Bs[2 * 128 * 64];
  const int tid = threadIdx.x;
  const int lane = tid & 63, wave = tid >> 6;
  const int tn = N >> 7;
  const int bm = (int)blockIdx.x / tn, bn = (int)blockIdx.x % tn;
  const int wm = (wave >> 1) << 6, wn = (wave & 1) << 6;
  const int lr = lane & 15, lk = lane >> 4;

  f32x4 acc[4][4];
#pragma unroll
  for (int i = 0; i < 4; ++i)
#pragma unroll
    for (int j = 0; j < 4; ++j) acc[i][j] = (f32x4){0.f, 0.f, 0.f, 0.f};

  auto stageAB = [&](int nb, int k0) {
#pragma unroll
    for (int i = 0; i < 4; ++i) {
      const int cb = (i << 2) + wave;
      const int id = (cb << 6) + lane;
      const int row = id >> 3, ck = id & 7;
      const int gk = k0 + ((ck ^ (row & 7)) << 3);
      const unsigned short* srcA;
      if (A1) {
        srcA = (gk < 256) ? (A0 + (size_t)(bm * 128 + row) * 256 + gk)
                          : (A1 + (size_t)(bm * 128 + row) * 256 + (gk - 256));
      } else {
        srcA = A0 + (size_t)(bm * 128 + row) * lda + gk;
      }
      gload_lds16(srcA, As + nb * 8192 + (size_t)cb * 512);
      const unsigned short* srcB = BT + (size_t)(bn * 128 + row) * K + gk;
      gload_lds16(srcB, Bs + nb * 8192 + (size_t)cb * 512);
    }
  };

  const int nt = K >> 6;
  stageAB(0, 0);
  __syncthreads();
  int cur = 0;
  for (int t = 0; t < nt; ++t) {
    if (t + 1 < nt) stageAB(cur ^ 1, (t + 1) << 6);
    const unsigned short* Ac = As + cur * 8192;
    const unsigned short* Bc = Bs + cur * 8192;
#pragma unroll
    for (int kk = 0; kk < 2; ++kk) {
      short8 af[4], bfr[4];
#pragma unroll
      for (int mi = 0; mi < 4; ++mi) {
        const int row = wm + mi * 16 + lr;
        const int ck = ((kk << 2) + lk) ^ (row & 7);
        af[mi] = *(const short8*)(Ac + row * 64 + ck * 8);
      }
#pragma unroll
      for (int ni = 0; ni < 4; ++ni) {
        const int row = wn + ni * 16 + lr;
        const int ck = ((kk << 2) + lk) ^ (row & 7);
        bfr[ni] = *(const short8*)(Bc + row * 64 + ck * 8);
      }
#pragma unroll
      for (int mi = 0; mi < 4; ++mi)
#pragma unroll
        for (int ni = 0; ni < 4; ++ni)
          acc[mi][ni] = __builtin_amdgcn_mfma_f32_16x16x32_bf16(af[mi], bfr[ni], acc[mi][ni], 0, 0, 0);
    }
    __syncthreads();
    cur ^= 1;
  }

  const int cr = lk << 2;
#pragma unroll
  for (int mi = 0; mi < 4; ++mi) {
#pragma unroll
    for (int ni = 0; ni < 4; ++ni) {
      const int colbase = bn * 128 + wn + ni * 16;
#pragma unroll
      for (int j = 0; j < 4; ++j) {
        const int row = bm * 128 + wm + mi * 16 + cr + j;
        const int col = colbase + lr;
        float v = acc[mi][ni][j];
        if (EPI == 1) {
          Cb[(size_t)row * N + col] = f2bf(fmaxf(v, 0.f));
        } else if (EPI == 2) {
          Cb[(size_t)row * N + col] = f2bf(colbase < 256 ? elu1(v) : v);
        } else if (EPI == 3) {
          Cb[(size_t)row * 256 + col] = f2bf(elu1(v));
        } else {  // 4
          if (colbase < 256) Cb[(size_t)row * 256 + col] = f2bf(elu1(v));
          else Cb2[(size_t)row * 512 + (col - 256)] = f2bf(colbase < 512 ? elu1(v) : v);
        }
      }
    }
  }
}

// ---------------- fused GEMM (N=256 exactly) + LayerNorm epilogue, double-buffered.
// BM=128, BN=256, 8 waves (512 thr). EPI 0: LN -> bf16; EPI 1: residual + LN -> f32 + bf16
template<int EPI>
__global__ __launch_bounds__(512)
void gemm_ln(const unsigned short* __restrict__ A, const unsigned short* __restrict__ BT,
             const float* __restrict__ lnw, const float* __restrict__ lnb,
             const float* __restrict__ xres, float* __restrict__ outf,
             unsigned short* __restrict__ outb, int K) {
  __shared__ __align__(16) unsigned short As[2 * 128 * 64];
  __shared__ __align__(16) unsigned short Bs[2 * 256 * 64];
  const int tid = threadIdx.x;
  const int lane = tid & 63, wid = tid >> 6;
  const int bm = blockIdx.x;
  const int wm = (wid >> 2) << 6, wn = (wid & 3) << 6;
  const int lr = lane & 15, lk = lane >> 4;

  f32x4 acc[4][4];
#pragma unroll
  for (int i = 0; i < 4; ++i)
#pragma unroll
    for (int j = 0; j < 4; ++j) acc[i][j] = (f32x4){0.f, 0.f, 0.f, 0.f};

  auto stageAB = [&](int nb, int k0) {
#pragma unroll
    for (int i = 0; i < 2; ++i) {
      const int cb = i * 8 + wid;
      const int id = (cb << 6) + lane;
      const int row = id >> 3, ck = id & 7;
      const int gk = k0 + ((ck ^ (row & 7)) << 3);
      gload_lds16(A + (size_t)(bm * 128 + row) * K + gk, As + nb * 8192 + (size_t)cb * 512);
    }
#pragma unroll
    for (int i = 0; i < 4; ++i) {
      const int cb = i * 8 + wid;
      const int id = (cb << 6) + lane;
      const int row = id >> 3, ck = id & 7;
      const int gk = k0 + ((ck ^ (row & 7)) << 3);
      gload_lds16(BT + (size_t)row * K + gk, Bs + nb * 16384 + (size_t)cb * 512);
    }
  };

  const int nt = K >> 6;
  stageAB(0, 0);
  __syncthreads();
  int cur = 0;
  for (int t = 0; t < nt; ++t) {
    if (t + 1 < nt) stageAB(cur ^ 1, (t + 1) << 6);
    const unsigned short* Ac = As + cur * 8192;
    const unsigned short* Bc = Bs + cur * 16384;
#pragma unroll
    for (int kk = 0; kk < 2; ++kk) {
      short8 af[4], bfr[4];
#pragma unroll
      for (int mi = 0; mi < 4; ++mi) {
        const int row = wm + mi * 16 + lr;
        const int ck = ((kk << 2) + lk) ^ (row & 7);
        af[mi] = *(const short8*)(Ac + row * 64 + ck * 8);
      }
#pragma unroll
      for (int ni = 0; ni < 4; ++ni) {
        const int row = wn + ni * 16 + lr;
        const int ck = ((kk << 2) + lk) ^ (row & 7);
        bfr[ni] = *(const short8*)(Bc + row * 64 + ck * 8);
      }
#pragma unroll
      for (int mi = 0; mi < 4; ++mi)
#pragma unroll
        for (int ni = 0; ni < 4; ++ni)
          acc[mi][ni] = __builtin_amdgcn_mfma_f32_16x16x32_bf16(af[mi], bfr[ni], acc[mi][ni], 0, 0, 0);
    }
    __syncthreads();
    cur ^= 1;
  }

  // ---- cross-wave LN reduce (rows complete within block; 4 wn-groups per row)
  float* red = (float*)As;  // [128][8]: per row, 4 x (sum, sumsq)
  float wv[4], bv[4];
#pragma unroll
  for (int ni = 0; ni < 4; ++ni) {
    wv[ni] = lnw[wn + ni * 16 + lr];
    bv[ni] = lnb[wn + ni * 16 + lr];
  }
#pragma unroll
  for (int mi = 0; mi < 4; ++mi) {
#pragma unroll
    for (int j = 0; j < 4; ++j) {
      float s = 0.f, q = 0.f;
#pragma unroll
      for (int ni = 0; ni < 4; ++ni) {
        float v = acc[mi][ni][j];
        s += v; q += v * v;
      }
#pragma unroll
      for (int o = 1; o < 16; o <<= 1) {
        s += __shfl_xor(s, o);
        q += __shfl_xor(q, o);
      }
      if (lr == 0) {
        int row = wm + mi * 16 + (lk << 2) + j;
        red[row * 8 + (wid & 3) * 2] = s;
        red[row * 8 + (wid & 3) * 2 + 1] = q;
      }
    }
  }
  __syncthreads();
#pragma unroll
  for (int mi = 0; mi < 4; ++mi) {
#pragma unroll
    for (int j = 0; j < 4; ++j) {
      const int row = wm + mi * 16 + (lk << 2) + j;
      const size_t grow = (size_t)bm * 128 + row;
      float s = red[row * 8] + red[row * 8 + 2] + red[row * 8 + 4] + red[row * 8 + 6];
      float q = red[row * 8 + 1] + red[row * 8 + 3] + red[row * 8 + 5] + red[row * 8 + 7];
      float mu = s * (1.f / 256.f);
      float var = q * (1.f / 256.f) - mu * mu;
      float rstd = rsqrtf(var + 1e-5f);
#pragma unroll
      for (int ni = 0; ni < 4; ++ni) {
        int col = wn + ni * 16 + lr;
        float y = (acc[mi][ni][j] - mu) * rstd * wv[ni] + bv[ni];
        if (EPI == 0) {
          outb[grow * 256 + col] = f2bf(y);
        } else {
          float o = xres[grow * 256 + col] + y;
          outf[grow * 256 + col] = o;
          outb[grow * 256 + col] = f2bf(o);
        }
      }
    }
  }
}

// ---------------- KV partial reduction from bf16 kv buffer [row][512] = [K(elu)|V]
__global__ __launch_bounds__(256)
void kv_partial(const unsigned short* __restrict__ kvb, float* __restrict__ part) {
  const int ch = blockIdx.x, h = blockIdx.y, n = blockIdx.z;
  const int t = threadIdx.x, wave = t >> 6, lane = t & 63;
  __shared__ float kb[4][8][36];
  __shared__ float vb[4][8][36];
  const int dq = lane >> 3, vq = lane & 7;
  float a[4][4];
  float ks[4] = {0.f, 0.f, 0.f, 0.f};
#pragma unroll
  for (int i = 0; i < 4; ++i)
#pragma unroll
    for (int j = 0; j < 4; ++j) a[i][j] = 0.f;

  const int s_base = ch * 480 + wave * 120;
  const int half = lane >> 5, l = lane & 31, r = l >> 2, c8 = l & 3;
  const unsigned short* src = kvb + ((size_t)n * 4800 + s_base + r) * 512 +
                              half * 256 + h * 32 + c8 * 8;
  float* dst = (half ? &vb[wave][r][0] : &kb[wave][r][0]) + c8 * 8;

  for (int it = 0; it < 15; ++it) {
    __syncthreads();
    short8 raw = *(const short8*)(src + (size_t)it * 8 * 512);
#pragma unroll
    for (int e = 0; e < 8; ++e) dst[e] = bf2f((unsigned short)raw[e]);
    __syncthreads();
#pragma unroll
    for (int si = 0; si < 8; ++si) {
      float4 kq = *(const float4*)&kb[wave][si][dq * 4];
      float4 vv = *(const float4*)&vb[wave][si][vq * 4];
      ks[0] += kq.x; ks[1] += kq.y; ks[2] += kq.z; ks[3] += kq.w;
      a[0][0] += kq.x * vv.x; a[0][1] += kq.x * vv.y; a[0][2] += kq.x * vv.z; a[0][3] += kq.x * vv.w;
      a[1][0] += kq.y * vv.x; a[1][1] += kq.y * vv.y; a[1][2] += kq.y * vv.z; a[1][3] += kq.y * vv.w;
      a[2][0] += kq.z * vv.x; a[2][1] += kq.z * vv.y; a[2][2] += kq.z * vv.z; a[2][3] += kq.z * vv.w;
      a[3][0] += kq.w * vv.x; a[3][1] += kq.w * vv.y; a[3][2] += kq.w * vv.z; a[3][3] += kq.w * vv.w;
    }
  }
  float* pb = part + ((size_t)((n * 8 + h) * 40 + ch * 4 + wave)) * 1056;
#pragma unroll
  for (int i = 0; i < 4; ++i) {
#pragma unroll
    for (int j = 0; j < 4; ++j) pb[(dq * 4 + i) * 32 + vq * 4 + j] = a[i][j];
    if (vq == 0) pb[1024 + dq * 4 + i] = ks[i];
  }
}

// ---------------- reduce 40 partials; KV written bf16 in exact MFMA B-fragment order
__global__ __launch_bounds__(256)
void kv_reduce(const float* __restrict__ part, unsigned short* __restrict__ KVb,
               float* __restrict__ Ksum) {
  const int nh = blockIdx.x, t = threadIdx.x;
  const float* pb = part + (size_t)nh * 40 * 1056;
#pragma unroll
  for (int j = 0; j < 4; ++j) {
    int e = t * 4 + j;
    float s = 0.f;
    for (int c = 0; c < 40; ++c) s += pb[c * 1056 + e];
    int dd = e >> 5, vv = e & 31;
    size_t addr = ((size_t)(nh * 2 + (vv >> 4)) * 64 + ((dd >> 3) * 16 + (vv & 15))) * 8 + (dd & 7);
    KVb[addr] = f2bf(s);
  }
  if (t < 32) {
    float s = 0.f;
    for (int c = 0; c < 40; ++c) s += pb[c * 1056 + 1024 + t];
    Ksum[nh * 32 + t] = s;
  }
}

// ---------------- msg = (Q @ KV) * z, z = 1/(Q.Ksum + 1e-6); Q already elu'd, bf16
__global__ __launch_bounds__(256)
void msg_kernel(const unsigned short* __restrict__ qb, const unsigned short* __restrict__ KVb,
                const float* __restrict__ Ksum, unsigned short* __restrict__ msg, int qoff) {
  const int n = blockIdx.y;
  const int wave = threadIdx.x >> 6, lane = threadIdx.x & 63;
  const int lr = lane & 15, lk = lane >> 4;
  const int lrow = blockIdx.x * 64 + wave * 16 + lr;
  const unsigned short* qrow = qb + ((size_t)qoff + (size_t)n * 4800 + lrow) * 256;
  const short8* kvv = (const short8*)KVb;
  for (int h = 0; h < 8; ++h) {
    short8 af = *(const short8*)(qrow + h * 32 + lk * 8);
    const float* ksp = Ksum + (n * 8 + h) * 32 + lk * 8;
    float zp = 0.f;
#pragma unroll
    for (int j = 0; j < 8; ++j) zp += bf2f((unsigned short)af[j]) * ksp[j];
    zp += __shfl_xor(zp, 16);
    zp += __shfl_xor(zp, 32);
    float z = 1.f / (zp + 1e-6f);
    short8 b0 = kvv[((size_t)(n * 8 + h) * 2 + 0) * 64 + lane];
    short8 b1 = kvv[((size_t)(n * 8 + h) * 2 + 1) * 64 + lane];
    f32x4 acc0 = (f32x4){0.f, 0.f, 0.f, 0.f}, acc1 = (f32x4){0.f, 0.f, 0.f, 0.f};
    acc0 = __builtin_amdgcn_mfma_f32_16x16x32_bf16(af, b0, acc0, 0, 0, 0);
    acc1 = __builtin_amdgcn_mfma_f32_16x16x32_bf16(af, b1, acc1, 0, 0, 0);
#pragma unroll
    for (int j = 0; j < 4; ++j) {
      int rr = lk * 4 + j;
      float zj = __shfl(z, rr);
      int row = blockIdx.x * 64 + wave * 16 + rr;
      size_t base = ((size_t)n * 4800 + row) * 256 + h * 32;
      msg[base + lr] = f2bf(acc0[j] * zj);
      msg[base + 16 + lr] = f2bf(acc1[j] * zj);
    }
  }
}

extern "C" void kernel_launch(void* const* d_in, const int* in_sizes, int n_in,
                              void* d_out, int out_size, void* d_ws, size_t ws_size,
                              hipStream_t stream) {
  (void)in_sizes; (void)n_in; (void)out_size; (void)ws_size;
  const float* feat0 = (const float*)d_in[0];
  const float* feat1 = (const float*)d_in[1];
  const float* Wq = (const float*)d_in[2];
  const float* Wk = (const float*)d_in[3];
  const float* Wv = (const float*)d_in[4];
  const float* Wm = (const float*)d_in[5];
  const float* W1 = (const float*)d_in[6];
  const float* W2 = (const float*)d_in[7];
  const float* ln1w = (const float*)d_in[8];
  const float* ln1b = (const float*)d_in[9];
  const float* ln2w = (const float*)d_in[10];
  const float* ln2b = (const float*)d_in[11];

  float* F0 = (float*)d_out;
  float* F1 = F0 + (size_t)4915200;

  size_t off = 0;
  auto alloc = [&](size_t bytes) -> void* {
    void* p = (char*)d_ws + off;
    off += (bytes + 255) & ~(size_t)255;
    return p;
  };
  unsigned short* Fb     = (unsigned short*)alloc((size_t)38400 * 256 * 2);
  unsigned short* qb     = (unsigned short*)alloc((size_t)38400 * 256 * 2);
  unsigned short* kvb    = (unsigned short*)alloc((size_t)38400 * 512 * 2);  // also h1b
  unsigned short* msgb   = (unsigned short*)alloc((size_t)38400 * 256 * 2);
  unsigned short* msglnb = (unsigned short*)alloc((size_t)38400 * 256 * 2);
  float*          part   = (float*)alloc((size_t)64 * 40 * 1056 * 4);
  unsigned short* KVb    = (unsigned short*)alloc((size_t)65536 * 2);
  float*          Ksum   = (float*)alloc((size_t)2048 * 4);
  unsigned short* WqkvT  = (unsigned short*)alloc((size_t)8 * 196608 * 2);
  unsigned short* WmT    = (unsigned short*)alloc((size_t)8 * 65536 * 2);
  unsigned short* W1T    = (unsigned short*)alloc((size_t)8 * 262144 * 2);
  unsigned short* W2T    = (unsigned short*)alloc((size_t)8 * 131072 * 2);
  unsigned short* h1b = kvb;
  unsigned short* F0b = Fb;
  unsigned short* F1b = Fb + (size_t)19200 * 256;

  init_feat<<<4800, 256, 0, stream>>>(feat0, F0, F0b, 1228800);
  init_feat<<<4800, 256, 0, stream>>>(feat1, F1, F1b, 1228800);

  wprep<<<dim3(4, 4, 8), 256, 0, stream>>>(Wq, WqkvT, 256, 256, 196608);
  wprep<<<dim3(4, 4, 8), 256, 0, stream>>>(Wk, WqkvT + 65536, 256, 256, 196608);
  wprep<<<dim3(4, 4, 8), 256, 0, stream>>>(Wv, WqkvT + 131072, 256, 256, 196608);
  wprep<<<dim3(4, 4, 8), 256, 0, stream>>>(Wm, WmT, 256, 256, 65536);
  wprep<<<dim3(8, 8, 8), 256, 0, stream>>>(W1, W1T, 512, 512, 262144);
  wprep<<<dim3(4, 8, 8), 256, 0, stream>>>(W2, W2T, 512, 256, 131072);

  // ---- self pair, batched M=38400
  auto enc_self = [&](int i) {
    gemm_bt<4><<<1800, 256, 0, stream>>>(Fb, nullptr, WqkvT + (size_t)i * 196608,
                                         qb, kvb, 38400, 768, 256, 256);
    kv_partial<<<dim3(10, 8, 8), 256, 0, stream>>>(kvb, part);
    kv_reduce<<<64, 256, 0, stream>>>(part, KVb, Ksum);
    msg_kernel<<<dim3(75, 8), 256, 0, stream>>>(qb, KVb, Ksum, msgb, 0);
    gemm_ln<0><<<300, 512, 0, stream>>>(msgb, WmT + (size_t)i * 65536,
                                        ln1w + i * 256, ln1b + i * 256,
                                        nullptr, nullptr, msglnb, 256);
    gemm_bt<1><<<1200, 256, 0, stream>>>(Fb, msglnb, W1T + (size_t)i * 262144,
                                         h1b, nullptr, 38400, 512, 512, 256);
    gemm_ln<1><<<300, 512, 0, stream>>>(h1b, W2T + (size_t)i * 131072,
                                        ln2w + i * 256, ln2b + i * 256,
                                        F0, F0, Fb, 512);
  };

  // ---- one cross enc (M=19200)
  auto enc_cross = [&](float* X, unsigned short* Xb, unsigned short* Sb, int i) {
    gemm_bt<3><<<300, 256, 0, stream>>>(Xb, nullptr, WqkvT + (size_t)i * 196608,
                                        qb, nullptr, 19200, 256, 256, 256);
    gemm_bt<2><<<600, 256, 0, stream>>>(Sb, nullptr, WqkvT + (size_t)i * 196608 + 65536,
                                        kvb, nullptr, 19200, 512, 256, 256);
    kv_partial<<<dim3(10, 8, 4), 256, 0, stream>>>(kvb, part);
    kv_reduce<<<32, 256, 0, stream>>>(part, KVb, Ksum);
    msg_kernel<<<dim3(75, 4), 256, 0, stream>>>(qb, KVb, Ksum, msgb, 0);
    gemm_ln<0><<<150, 512, 0, stream>>>(msgb, WmT + (size_t)i * 65536,
                                        ln1w + i * 256, ln1b + i * 256,
                                        nullptr, nullptr, msglnb, 256);
    gemm_bt<1><<<600, 256, 0, stream>>>(Xb, msglnb, W1T + (size_t)i * 262144,
                                        h1b, nullptr, 19200, 512, 512, 256);
    gemm_ln<1><<<150, 512, 0, stream>>>(h1b, W2T + (size_t)i * 131072,
                                        ln2w + i * 256, ln2b + i * 256,
                                        X, X, Xb, 512);
  };

  for (int i = 0; i < 8; ++i) {
    if ((i & 1) == 0) {
      enc_self(i);
    } else {
      enc_cross(F0, F0b, F1b, i);
      enc_cross(F1, F1b, F0b, i);
    }
  }
}

// Round 7
// 1633.006 us; speedup vs baseline: 1.1971x; 1.0956x over previous
//
#include <hip/hip_runtime.h>

typedef __attribute__((ext_vector_type(8))) short short8;
typedef __attribute__((ext_vector_type(4))) float f32x4;

#define DEV static __device__ __forceinline__

DEV unsigned short f2bf(float x) {
  union { float f; unsigned int u; } c; c.f = x;
  unsigned int r = c.u + 0x7fffu + ((c.u >> 16) & 1u);
  return (unsigned short)(r >> 16);
}
DEV float bf2f(unsigned short s) {
  union { unsigned int u; float f; } c; c.u = ((unsigned int)s) << 16;
  return c.f;
}
DEV float elu1(float x) { return x > 0.f ? x + 1.f : __expf(x); }

DEV void gload_lds16(const void* g, void* l) {
  __builtin_amdgcn_global_load_lds(
      (const __attribute__((address_space(1))) unsigned int*)g,
      (__attribute__((address_space(3))) unsigned int*)l, 16, 0, 0);
}

// ---------------- weight transpose + bf16 convert: dst[layer][N][K] = src[layer][K][N]
__global__ __launch_bounds__(256)
void wprep(const float* __restrict__ src, unsigned short* __restrict__ dst,
           int K, int N, int dls) {
  const int layer = blockIdx.z;
  src += (size_t)layer * K * N;
  dst += (size_t)layer * dls;
  __shared__ float tile[64][65];
  const int n0 = blockIdx.x * 64, k0 = blockIdx.y * 64;
  const int c = threadIdx.x & 63, r4 = threadIdx.x >> 6;
#pragma unroll
  for (int i = 0; i < 16; ++i) {
    int r = (i << 2) + r4;
    tile[r][c] = src[(size_t)(k0 + r) * N + n0 + c];
  }
  __syncthreads();
#pragma unroll
  for (int i = 0; i < 16; ++i) {
    int r = (i << 2) + r4;
    dst[(size_t)(n0 + r) * K + k0 + c] = f2bf(tile[c][r]);
  }
}

// ---------------- init: f32 copy + bf16 mirror
__global__ __launch_bounds__(256)
void init_feat(const float* __restrict__ src, float* __restrict__ dstf,
               unsigned short* __restrict__ dstb, int n4) {
  int i = blockIdx.x * 256 + threadIdx.x;
  if (i >= n4) return;
  float4 v = ((const float4*)src)[i];
  ((float4*)dstf)[i] = v;
  ushort4 o;
  o.x = f2bf(v.x); o.y = f2bf(v.y); o.z = f2bf(v.z); o.w = f2bf(v.w);
  ((ushort4*)dstb)[i] = o;
}

// ---------------- bf16 MFMA GEMM, BT input (B stored N x K), 128x128 tile, BK=64,
// single-buffered; coalesced LDS-packed epilogue.
// EPI: 1 = relu->bf16 (stride N); 2 = elu on col<256 ->bf16 (stride 512);
//      3 = elu->bf16 (stride 256); 4 = merged qkv (N=768): q->Cb (stride 256, elu),
//          k/v->Cb2 (stride 512, elu on k half)
template<int EPI>
__global__ __launch_bounds__(256)
void gemm_bt(const unsigned short* __restrict__ A0,
             const unsigned short* __restrict__ A1,   // concat half (k>=256), stride 256; or null
             const unsigned short* __restrict__ BT,
             unsigned short* __restrict__ Cb, unsigned short* __restrict__ Cb2,
             int M, int N, int K, int lda) {
  __shared__ __align__(16) unsigned short smem[16896];  // As[8192] Bs[8192]; epi: Ct[128][132]
  unsigned short* As = smem;
  unsigned short* Bs = smem + 8192;
  const int tid = threadIdx.x;
  const int lane = tid & 63, wave = tid >> 6;
  const int tn = N >> 7;
  const int bm = (int)blockIdx.x / tn, bn = (int)blockIdx.x % tn;
  const int wm = (wave >> 1) << 6, wn = (wave & 1) << 6;
  const int lr = lane & 15, lk = lane >> 4;

  f32x4 acc[4][4];
#pragma unroll
  for (int i = 0; i < 4; ++i)
#pragma unroll
    for (int j = 0; j < 4; ++j) acc[i][j] = (f32x4){0.f, 0.f, 0.f, 0.f};

  for (int k0 = 0; k0 < K; k0 += 64) {
#pragma unroll
    for (int i = 0; i < 4; ++i) {
      const int cb = (i << 2) + wave;          // wave-uniform chunk group
      const int id = (cb << 6) + lane;
      const int row = id >> 3, ck = id & 7;
      const int gk = k0 + ((ck ^ (row & 7)) << 3);
      const unsigned short* srcA;
      if (A1) {
        srcA = (gk < 256) ? (A0 + (size_t)(bm * 128 + row) * 256 + gk)
                          : (A1 + (size_t)(bm * 128 + row) * 256 + (gk - 256));
      } else {
        srcA = A0 + (size_t)(bm * 128 + row) * lda + gk;
      }
      gload_lds16(srcA, As + (size_t)cb * 512);
      const unsigned short* srcB = BT + (size_t)(bn * 128 + row) * K + gk;
      gload_lds16(srcB, Bs + (size_t)cb * 512);
    }
    __syncthreads();
#pragma unroll
    for (int kk = 0; kk < 2; ++kk) {
      short8 af[4], bfr[4];
#pragma unroll
      for (int mi = 0; mi < 4; ++mi) {
        const int row = wm + mi * 16 + lr;
        const int ck = ((kk << 2) + lk) ^ (row & 7);
        af[mi] = *(const short8*)(As + row * 64 + ck * 8);
      }
#pragma unroll
      for (int ni = 0; ni < 4; ++ni) {
        const int row = wn + ni * 16 + lr;
        const int ck = ((kk << 2) + lk) ^ (row & 7);
        bfr[ni] = *(const short8*)(Bs + row * 64 + ck * 8);
      }
#pragma unroll
      for (int mi = 0; mi < 4; ++mi)
#pragma unroll
        for (int ni = 0; ni < 4; ++ni)
          acc[mi][ni] = __builtin_amdgcn_mfma_f32_16x16x32_bf16(af[mi], bfr[ni], acc[mi][ni], 0, 0, 0);
    }
    __syncthreads();
  }

  // ---- block-uniform destination / activation
  unsigned short* dst;
  int cstride, colofs, act;  // act: 0 none, 1 relu, 2 elu
  if (EPI == 1)      { dst = Cb;  cstride = N;   colofs = bn * 128; act = 1; }
  else if (EPI == 2) { dst = Cb;  cstride = 512; colofs = bn * 128; act = (bn < 2) ? 2 : 0; }
  else if (EPI == 3) { dst = Cb;  cstride = 256; colofs = bn * 128; act = 2; }
  else {  // 4: N=768
    if (bn < 2) { dst = Cb;  cstride = 256; colofs = bn * 128;       act = 2; }
    else        { dst = Cb2; cstride = 512; colofs = bn * 128 - 256; act = (bn < 4) ? 2 : 0; }
  }

  // ---- pack activated bf16 tile into LDS (128 cols, stride 132), coalesced row stores
  unsigned short* Ct = smem;  // [128][132]
  const int cr = lk << 2;
#pragma unroll
  for (int mi = 0; mi < 4; ++mi)
#pragma unroll
    for (int ni = 0; ni < 4; ++ni)
#pragma unroll
      for (int j = 0; j < 4; ++j) {
        float v = acc[mi][ni][j];
        v = (act == 1) ? fmaxf(v, 0.f) : (act == 2) ? elu1(v) : v;
        Ct[(wm + mi * 16 + cr + j) * 132 + (wn + ni * 16 + lr)] = f2bf(v);
      }
  __syncthreads();
  const int rr = lane >> 4, cc8 = (lane & 15) << 3;
#pragma unroll
  for (int s = 0; s < 8; ++s) {
    const int rl = (wave << 5) + (s << 2) + rr;
    uint2 lo = *(const uint2*)(Ct + rl * 132 + cc8);
    uint2 hi = *(const uint2*)(Ct + rl * 132 + cc8 + 4);
    uint4 val = make_uint4(lo.x, lo.y, hi.x, hi.y);
    *(uint4*)(dst + (size_t)(bm * 128 + rl) * cstride + colofs + cc8) = val;
  }
}

// ---------------- fused GEMM (N=256 exactly) + LayerNorm epilogue.
// BM=64, BN=256, 4 waves (256 thr). EPI 0: LN -> bf16; EPI 1: residual + LN -> f32 + bf16
template<int EPI>
__global__ __launch_bounds__(256)
void gemm_ln(const unsigned short* __restrict__ A, const unsigned short* __restrict__ BT,
             const float* __restrict__ lnw, const float* __restrict__ lnb,
             const float* __restrict__ xres, float* __restrict__ outf,
             unsigned short* __restrict__ outb, int K) {
  // As[64x64]=4096; Bs[256x64]=16384 staged; epilogue Pt=[64][264]=16896 at Bs
  __shared__ __align__(16) unsigned short smem[4096 + 16896];
  unsigned short* As = smem;
  unsigned short* Bs = smem + 4096;
  const int tid = threadIdx.x;
  const int lane = tid & 63, wid = tid >> 6;
  const int bm = blockIdx.x;
  const int wn = wid << 6;
  const int lr = lane & 15, lk = lane >> 4;

  f32x4 acc[4][4];
#pragma unroll
  for (int i = 0; i < 4; ++i)
#pragma unroll
    for (int j = 0; j < 4; ++j) acc[i][j] = (f32x4){0.f, 0.f, 0.f, 0.f};

  for (int k0 = 0; k0 < K; k0 += 64) {
    // wave-uniform LDS dest (global_load_lds requirement, m104); lane only in source
#pragma unroll
    for (int i = 0; i < 2; ++i) {
      const int cb = (i << 2) + wid;           // 0..7
      const int id = (cb << 6) + lane;         // 0..511
      const int row = id >> 3, ck = id & 7;
      const int gk = k0 + ((ck ^ (row & 7)) << 3);
      gload_lds16(A + (size_t)(bm * 64 + row) * K + gk, As + (size_t)cb * 512);
    }
#pragma unroll
    for (int i = 0; i < 8; ++i) {
      const int cb = (i << 2) + wid;           // 0..31
      const int id = (cb << 6) + lane;         // 0..2047
      const int row = id >> 3, ck = id & 7;
      const int gk = k0 + ((ck ^ (row & 7)) << 3);
      gload_lds16(BT + (size_t)row * K + gk, Bs + (size_t)cb * 512);
    }
    __syncthreads();
#pragma unroll
    for (int kk = 0; kk < 2; ++kk) {
      short8 af[4], bfr[4];
#pragma unroll
      for (int mi = 0; mi < 4; ++mi) {
        const int row = mi * 16 + lr;
        const int ck = ((kk << 2) + lk) ^ (row & 7);
        af[mi] = *(const short8*)(As + row * 64 + ck * 8);
      }
#pragma unroll
      for (int ni = 0; ni < 4; ++ni) {
        const int row = wn + ni * 16 + lr;
        const int ck = ((kk << 2) + lk) ^ (row & 7);
        bfr[ni] = *(const short8*)(Bs + row * 64 + ck * 8);
      }
#pragma unroll
      for (int mi = 0; mi < 4; ++mi)
#pragma unroll
        for (int ni = 0; ni < 4; ++ni)
          acc[mi][ni] = __builtin_amdgcn_mfma_f32_16x16x32_bf16(af[mi], bfr[ni], acc[mi][ni], 0, 0, 0);
    }
    __syncthreads();
  }

  // ---- cross-wave LN reduce: red[64][8] floats in As region (2048 B < 8192 B)
  float* red = (float*)smem;
  const int cr = lk << 2;
  float wv[4], bv[4];
#pragma unroll
  for (int ni = 0; ni < 4; ++ni) {
    wv[ni] = lnw[wn + ni * 16 + lr];
    bv[ni] = lnb[wn + ni * 16 + lr];
  }
#pragma unroll
  for (int mi = 0; mi < 4; ++mi) {
#pragma unroll
    for (int j = 0; j < 4; ++j) {
      float s = 0.f, q = 0.f;
#pragma unroll
      for (int ni = 0; ni < 4; ++ni) {
        float v = acc[mi][ni][j];
        s += v; q += v * v;
      }
#pragma unroll
      for (int o = 1; o < 16; o <<= 1) {
        s += __shfl_xor(s, o);
        q += __shfl_xor(q, o);
      }
      if (lr == 0) {
        int row = mi * 16 + cr + j;
        red[row * 8 + wid * 2] = s;
        red[row * 8 + wid * 2 + 1] = q;
      }
    }
  }
  __syncthreads();

  unsigned short* Pt = Bs;  // [64][264] bf16 out tile (stride 264 >= 256 cols!)
#pragma unroll
  for (int mi = 0; mi < 4; ++mi) {
#pragma unroll
    for (int j = 0; j < 4; ++j) {
      const int row = mi * 16 + cr + j;
      const size_t grow = (size_t)bm * 64 + row;
      float s = red[row * 8] + red[row * 8 + 2] + red[row * 8 + 4] + red[row * 8 + 6];
      float q = red[row * 8 + 1] + red[row * 8 + 3] + red[row * 8 + 5] + red[row * 8 + 7];
      float mu = s * (1.f / 256.f);
      float var = q * (1.f / 256.f) - mu * mu;
      float rstd = rsqrtf(var + 1e-5f);
#pragma unroll
      for (int ni = 0; ni < 4; ++ni) {
        int col = wn + ni * 16 + lr;
        float y = (acc[mi][ni][j] - mu) * rstd * wv[ni] + bv[ni];
        if (EPI == 0) {
          Pt[row * 264 + col] = f2bf(y);
        } else {
          float o = xres[grow * 256 + col] + y;
          outf[grow * 256 + col] = o;
          Pt[row * 264 + col] = f2bf(o);
        }
      }
    }
  }
  __syncthreads();
  const int rr = lane >> 4, cc8 = (lane & 15) << 3;
#pragma unroll
  for (int s = 0; s < 4; ++s)
#pragma unroll
    for (int ch = 0; ch < 2; ++ch) {
      const int rl = (wid << 4) + (s << 2) + rr;
      const int col = (ch << 7) + cc8;
      uint2 lo = *(const uint2*)(Pt + rl * 264 + col);
      uint2 hi = *(const uint2*)(Pt + rl * 264 + col + 4);
      uint4 val = make_uint4(lo.x, lo.y, hi.x, hi.y);
      *(uint4*)(outb + (size_t)(bm * 64 + rl) * 256 + col) = val;
    }
}

// ---------------- KV partial reduction from bf16 kv buffer [row][512] = [K(elu)|V]
__global__ __launch_bounds__(256)
void kv_partial(const unsigned short* __restrict__ kvb, float* __restrict__ part) {
  const int ch = blockIdx.x, h = blockIdx.y, n = blockIdx.z;
  const int t = threadIdx.x, wave = t >> 6, lane = t & 63;
  __shared__ float kb[4][8][36];
  __shared__ float vb[4][8][36];
  const int dq = lane >> 3, vq = lane & 7;
  float a[4][4];
  float ks[4] = {0.f, 0.f, 0.f, 0.f};
#pragma unroll
  for (int i = 0; i < 4; ++i)
#pragma unroll
    for (int j = 0; j < 4; ++j) a[i][j] = 0.f;

  const int s_base = ch * 480 + wave * 120;
  const int half = lane >> 5, l = lane & 31, r = l >> 2, c8 = l & 3;
  const unsigned short* src = kvb + ((size_t)n * 4800 + s_base + r) * 512 +
                              half * 256 + h * 32 + c8 * 8;
  float* dst = (half ? &vb[wave][r][0] : &kb[wave][r][0]) + c8 * 8;

  for (int it = 0; it < 15; ++it) {
    __syncthreads();
    short8 raw = *(const short8*)(src + (size_t)it * 8 * 512);
#pragma unroll
    for (int e = 0; e < 8; ++e) dst[e] = bf2f((unsigned short)raw[e]);
    __syncthreads();
#pragma unroll
    for (int si = 0; si < 8; ++si) {
      float4 kq = *(const float4*)&kb[wave][si][dq * 4];
      float4 vv = *(const float4*)&vb[wave][si][vq * 4];
      ks[0] += kq.x; ks[1] += kq.y; ks[2] += kq.z; ks[3] += kq.w;
      a[0][0] += kq.x * vv.x; a[0][1] += kq.x * vv.y; a[0][2] += kq.x * vv.z; a[0][3] += kq.x * vv.w;
      a[1][0] += kq.y * vv.x; a[1][1] += kq.y * vv.y; a[1][2] += kq.y * vv.z; a[1][3] += kq.y * vv.w;
      a[2][0] += kq.z * vv.x; a[2][1] += kq.z * vv.y; a[2][2] += kq.z * vv.z; a[2][3] += kq.z * vv.w;
      a[3][0] += kq.w * vv.x; a[3][1] += kq.w * vv.y; a[3][2] += kq.w * vv.z; a[3][3] += kq.w * vv.w;
    }
  }
  float* pb = part + ((size_t)((n * 8 + h) * 40 + ch * 4 + wave)) * 1056;
#pragma unroll
  for (int i = 0; i < 4; ++i) {
#pragma unroll
    for (int j = 0; j < 4; ++j) pb[(dq * 4 + i) * 32 + vq * 4 + j] = a[i][j];
    if (vq == 0) pb[1024 + dq * 4 + i] = ks[i];
  }
}

// ---------------- reduce 40 partials; KV written bf16 in exact MFMA B-fragment order
__global__ __launch_bounds__(256)
void kv_reduce(const float* __restrict__ part, unsigned short* __restrict__ KVb,
               float* __restrict__ Ksum) {
  const int nh = blockIdx.x, t = threadIdx.x;
  const float* pb = part + (size_t)nh * 40 * 1056;
#pragma unroll
  for (int j = 0; j < 4; ++j) {
    int e = t * 4 + j;
    float s = 0.f;
    for (int c = 0; c < 40; ++c) s += pb[c * 1056 + e];
    int dd = e >> 5, vv = e & 31;
    size_t addr = ((size_t)(nh * 2 + (vv >> 4)) * 64 + ((dd >> 3) * 16 + (vv & 15))) * 8 + (dd & 7);
    KVb[addr] = f2bf(s);
  }
  if (t < 32) {
    float s = 0.f;
    for (int c = 0; c < 40; ++c) s += pb[c * 1056 + 1024 + t];
    Ksum[nh * 32 + t] = s;
  }
}

// ---------------- msg = (Q @ KV) * z, z = 1/(Q.Ksum + 1e-6); Q already elu'd, bf16
__global__ __launch_bounds__(256)
void msg_kernel(const unsigned short* __restrict__ qb, const unsigned short* __restrict__ KVb,
                const float* __restrict__ Ksum, unsigned short* __restrict__ msg, int qoff) {
  const int n = blockIdx.y;
  const int wave = threadIdx.x >> 6, lane = threadIdx.x & 63;
  const int lr = lane & 15, lk = lane >> 4;
  const int lrow = blockIdx.x * 64 + wave * 16 + lr;
  const unsigned short* qrow = qb + ((size_t)qoff + (size_t)n * 4800 + lrow) * 256;
  const short8* kvv = (const short8*)KVb;
  for (int h = 0; h < 8; ++h) {
    short8 af = *(const short8*)(qrow + h * 32 + lk * 8);
    const float* ksp = Ksum + (n * 8 + h) * 32 + lk * 8;
    float zp = 0.f;
#pragma unroll
    for (int j = 0; j < 8; ++j) zp += bf2f((unsigned short)af[j]) * ksp[j];
    zp += __shfl_xor(zp, 16);
    zp += __shfl_xor(zp, 32);
    float z = 1.f / (zp + 1e-6f);
    short8 b0 = kvv[((size_t)(n * 8 + h) * 2 + 0) * 64 + lane];
    short8 b1 = kvv[((size_t)(n * 8 + h) * 2 + 1) * 64 + lane];
    f32x4 acc0 = (f32x4){0.f, 0.f, 0.f, 0.f}, acc1 = (f32x4){0.f, 0.f, 0.f, 0.f};
    acc0 = __builtin_amdgcn_mfma_f32_16x16x32_bf16(af, b0, acc0, 0, 0, 0);
    acc1 = __builtin_amdgcn_mfma_f32_16x16x32_bf16(af, b1, acc1, 0, 0, 0);
#pragma unroll
    for (int j = 0; j < 4; ++j) {
      int rr = lk * 4 + j;
      float zj = __shfl(z, rr);
      int row = blockIdx.x * 64 + wave * 16 + rr;
      size_t base = ((size_t)n * 4800 + row) * 256 + h * 32;
      msg[base + lr] = f2bf(acc0[j] * zj);
      msg[base + 16 + lr] = f2bf(acc1[j] * zj);
    }
  }
}

extern "C" void kernel_launch(void* const* d_in, const int* in_sizes, int n_in,
                              void* d_out, int out_size, void* d_ws, size_t ws_size,
                              hipStream_t stream) {
  (void)in_sizes; (void)n_in; (void)out_size; (void)ws_size;
  const float* feat0 = (const float*)d_in[0];
  const float* feat1 = (const float*)d_in[1];
  const float* Wq = (const float*)d_in[2];
  const float* Wk = (const float*)d_in[3];
  const float* Wv = (const float*)d_in[4];
  const float* Wm = (const float*)d_in[5];
  const float* W1 = (const float*)d_in[6];
  const float* W2 = (const float*)d_in[7];
  const float* ln1w = (const float*)d_in[8];
  const float* ln1b = (const float*)d_in[9];
  const float* ln2w = (const float*)d_in[10];
  const float* ln2b = (const float*)d_in[11];

  float* F0 = (float*)d_out;
  float* F1 = F0 + (size_t)4915200;

  size_t off = 0;
  auto alloc = [&](size_t bytes) -> void* {
    void* p = (char*)d_ws + off;
    off += (bytes + 255) & ~(size_t)255;
    return p;
  };
  unsigned short* Fb     = (unsigned short*)alloc((size_t)38400 * 256 * 2);
  unsigned short* qb     = (unsigned short*)alloc((size_t)38400 * 256 * 2);
  unsigned short* kvb    = (unsigned short*)alloc((size_t)38400 * 512 * 2);  // also h1b
  unsigned short* msgb   = (unsigned short*)alloc((size_t)38400 * 256 * 2);
  unsigned short* msglnb = (unsigned short*)alloc((size_t)38400 * 256 * 2);
  float*          part   = (float*)alloc((size_t)64 * 40 * 1056 * 4);
  unsigned short* KVb    = (unsigned short*)alloc((size_t)65536 * 2);
  float*          Ksum   = (float*)alloc((size_t)2048 * 4);
  unsigned short* WqkvT  = (unsigned short*)alloc((size_t)8 * 196608 * 2);
  unsigned short* WmT    = (unsigned short*)alloc((size_t)8 * 65536 * 2);
  unsigned short* W1T    = (unsigned short*)alloc((size_t)8 * 262144 * 2);
  unsigned short* W2T    = (unsigned short*)alloc((size_t)8 * 131072 * 2);
  unsigned short* h1b = kvb;
  unsigned short* F0b = Fb;
  unsigned short* F1b = Fb + (size_t)19200 * 256;

  init_feat<<<4800, 256, 0, stream>>>(feat0, F0, F0b, 1228800);
  init_feat<<<4800, 256, 0, stream>>>(feat1, F1, F1b, 1228800);

  wprep<<<dim3(4, 4, 8), 256, 0, stream>>>(Wq, WqkvT, 256, 256, 196608);
  wprep<<<dim3(4, 4, 8), 256, 0, stream>>>(Wk, WqkvT + 65536, 256, 256, 196608);
  wprep<<<dim3(4, 4, 8), 256, 0, stream>>>(Wv, WqkvT + 131072, 256, 256, 196608);
  wprep<<<dim3(4, 4, 8), 256, 0, stream>>>(Wm, WmT, 256, 256, 65536);
  wprep<<<dim3(8, 8, 8), 256, 0, stream>>>(W1, W1T, 512, 512, 262144);
  wprep<<<dim3(4, 8, 8), 256, 0, stream>>>(W2, W2T, 512, 256, 131072);

  // FFN tail: msg -> Wm+LN1 -> W1(relu) -> W2+LN2(+residual). M rows.
  auto ffn = [&](unsigned short* Xb, float* X, int M, int i) {
    const int g64 = M >> 6, g128 = M >> 7;
    gemm_ln<0><<<g64, 256, 0, stream>>>(msgb, WmT + (size_t)i * 65536,
                                        ln1w + i * 256, ln1b + i * 256,
                                        nullptr, nullptr, msglnb, 256);
    gemm_bt<1><<<g128 * 4, 256, 0, stream>>>(Xb, msglnb, W1T + (size_t)i * 262144,
                                             h1b, nullptr, M, 512, 512, 256);
    gemm_ln<1><<<g64, 256, 0, stream>>>(h1b, W2T + (size_t)i * 131072,
                                        ln2w + i * 256, ln2b + i * 256,
                                        X, X, Xb, 512);
  };

  for (int i = 0; i < 8; ++i) {
    if ((i & 1) == 0) {
      // ---- self pair, batched M=38400: q + k/v in one GEMM
      gemm_bt<4><<<1800, 256, 0, stream>>>(Fb, nullptr, WqkvT + (size_t)i * 196608,
                                           qb, kvb, 38400, 768, 256, 256);
      kv_partial<<<dim3(10, 8, 8), 256, 0, stream>>>(kvb, part);
      kv_reduce<<<64, 256, 0, stream>>>(part, KVb, Ksum);
      msg_kernel<<<dim3(75, 8), 256, 0, stream>>>(qb, KVb, Ksum, msgb, 0);
      ffn(Fb, F0, 38400, i);
    } else {
      // batched Q for both features (x-side features unchanged by this layer's partner update)
      gemm_bt<3><<<600, 256, 0, stream>>>(Fb, nullptr, WqkvT + (size_t)i * 196608,
                                          qb, nullptr, 38400, 256, 256, 256);
      // F0 attends to old F1
      gemm_bt<2><<<600, 256, 0, stream>>>(F1b, nullptr, WqkvT + (size_t)i * 196608 + 65536,
                                          kvb, nullptr, 19200, 512, 256, 256);
      kv_partial<<<dim3(10, 8, 4), 256, 0, stream>>>(kvb, part);
      kv_reduce<<<32, 256, 0, stream>>>(part, KVb, Ksum);
      msg_kernel<<<dim3(75, 4), 256, 0, stream>>>(qb, KVb, Ksum, msgb, 0);
      ffn(F0b, F0, 19200, i);
      // F1 attends to updated F0
      gemm_bt<2><<<600, 256, 0, stream>>>(F0b, nullptr, WqkvT + (size_t)i * 196608 + 65536,
                                          kvb, nullptr, 19200, 512, 256, 256);
      kv_partial<<<dim3(10, 8, 4), 256, 0, stream>>>(kvb, part);
      kv_reduce<<<32, 256, 0, stream>>>(part, KVb, Ksum);
      msg_kernel<<<dim3(75, 4), 256, 0, stream>>>(qb, KVb, Ksum, msgb, 19200);
      ffn(F1b, F1, 19200, i);
    }
  }
}